// Round 4
// baseline (799.546 us; speedup 1.0000x reference)
//
#include <hip/hip_runtime.h>
#include <cstdint>
#include <cstddef>

// Problem constants: BS=512, EN=512, SEQ=64, D_ENT=256, D_IN=1024, D_KEY=32, D_F=256, H=32

typedef short bf16x8 __attribute__((ext_vector_type(8)));
typedef float f32x4  __attribute__((ext_vector_type(4)));

__device__ __forceinline__ ushort f2bf(float f) {
    union { float f; unsigned u; } x; x.f = f;
    unsigned r = x.u + 0x7fffu + ((x.u >> 16) & 1u);   // round-to-nearest-even
    return (ushort)(r >> 16);
}
__device__ __forceinline__ float bf2f(ushort u) {
    union { unsigned u; float f; } x; x.u = ((unsigned)u) << 16; return x.f;
}

__device__ __forceinline__ void gld16(const void* g, void* l) {
    __builtin_amdgcn_global_load_lds(
        (const __attribute__((address_space(1))) void*)g,
        (__attribute__((address_space(3))) void*)l,
        16, 0, 0);
}

// ---------------------------------------------------------------------------
// bf16 MFMA GEMM (used for the key GEMM only now).
// B pre-transposed as BT[N,K] bf16. A fp32 (load+cvt staging).
// KEYMODE remaps out row r=b*512+n into key layout [b][513][32], bf16 out.
// ---------------------------------------------------------------------------
template<int BM, int BN, int BK, int WR, int WC,
         bool RELU, bool OUT_BF16, bool A_F32, bool KEYMODE>
__global__ __launch_bounds__(WR * WC * 64)
void mfma_gemm(const void* __restrict__ Av, int lda,
               const ushort* __restrict__ BT,
               const float* __restrict__ bias,
               void* __restrict__ outv, int ldo, int K)
{
    constexpr int NT  = WR * WC * 64;
    constexpr int WM  = BM / WR, WN = BN / WC;
    constexpr int TMt = WM / 16, TNt = WN / 16;
    constexpr int KC  = BK / 8;
    constexpr int CHA = BM * KC, CHB = BN * KC;
    __shared__ __align__(16) ushort As[BM * BK];
    __shared__ __align__(16) ushort Bs[BN * BK];

    const int tid  = threadIdx.x;
    const int lane = tid & 63;
    const int w    = tid >> 6;
    const int wr   = w / WC, wc = w % WC;
    const int row0 = blockIdx.x * BM;
    const int n0   = blockIdx.y * BN;

    f32x4 acc[TMt][TNt];
#pragma unroll
    for (int i = 0; i < TMt; i++)
#pragma unroll
        for (int j = 0; j < TNt; j++)
#pragma unroll
            for (int r = 0; r < 4; r++) acc[i][j][r] = 0.f;

    const ushort* Ab = (const ushort*)Av;
    const float*  Af = (const float*)Av;

    for (int k0 = 0; k0 < K; k0 += BK) {
        if (A_F32) {
#pragma unroll
            for (int id = tid; id < CHA; id += NT) {
                int r = id / KC, kc = id % KC;
                const float* src = Af + (size_t)(row0 + r) * lda + k0 + kc * 8;
                float4 v0 = *(const float4*)(src);
                float4 v1 = *(const float4*)(src + 4);
                bf16x8 p;
                p[0] = (short)f2bf(v0.x); p[1] = (short)f2bf(v0.y);
                p[2] = (short)f2bf(v0.z); p[3] = (short)f2bf(v0.w);
                p[4] = (short)f2bf(v1.x); p[5] = (short)f2bf(v1.y);
                p[6] = (short)f2bf(v1.z); p[7] = (short)f2bf(v1.w);
                *(bf16x8*)(&As[id * 8]) = p;
            }
        } else {
#pragma unroll
            for (int id = tid; id < CHA; id += NT) {
                int r = id / KC, kc = id % KC;
                gld16(Ab + (size_t)(row0 + r) * lda + k0 + kc * 8, &As[id * 8]);
            }
        }
#pragma unroll
        for (int id = tid; id < CHB; id += NT) {
            int r = id / KC, kc = id % KC;
            gld16(BT + (size_t)(n0 + r) * K + k0 + kc * 8, &Bs[id * 8]);
        }
        __syncthreads();

        bf16x8 afr[TMt], bfr[TNt];
        const int krd = (lane >> 4) * 8;
        const int mrd = lane & 15;
#pragma unroll
        for (int tm = 0; tm < TMt; tm++)
            afr[tm] = *(bf16x8*)(&As[(wr * WM + tm * 16 + mrd) * BK + krd]);
#pragma unroll
        for (int tn = 0; tn < TNt; tn++)
            bfr[tn] = *(bf16x8*)(&Bs[(wc * WN + tn * 16 + mrd) * BK + krd]);
#pragma unroll
        for (int tm = 0; tm < TMt; tm++)
#pragma unroll
            for (int tn = 0; tn < TNt; tn++)
                acc[tm][tn] = __builtin_amdgcn_mfma_f32_16x16x32_bf16(
                    afr[tm], bfr[tn], acc[tm][tn], 0, 0, 0);
        __syncthreads();
    }

    float*  outf = (float*)outv;
    ushort* outh = (ushort*)outv;
    const int cn = lane & 15;
    const int rb = (lane >> 4) * 4;
#pragma unroll
    for (int tm = 0; tm < TMt; tm++) {
#pragma unroll
        for (int r = 0; r < 4; r++) {
            int grow = row0 + wr * WM + tm * 16 + rb + r;
            int b_   = grow & 511;
#pragma unroll
            for (int tn = 0; tn < TNt; tn++) {
                int gcol = n0 + wc * WN + tn * 16 + cn;
                float v = acc[tm][tn][r] + bias[gcol];
                if (RELU) v = fmaxf(v, 0.f);
                size_t oidx;
                if (KEYMODE) oidx = ((size_t)(grow >> 9) * 513 + b_) * 32 + gcol;
                else         oidx = (size_t)grow * ldo + gcol;
                if (OUT_BF16) outh[oidx] = f2bf(v);
                else          outf[oidx] = v;
            }
        }
    }
}

// ---------------------------------------------------------------------------
// fused_e: AE[512+row] = ar[row&511] + relu(EMB[row]@e1 + e1b)@e2 + e2b
// Z1 tile (128x256) lives in LDS. Grid: 252 blocks of 256 threads.
// ---------------------------------------------------------------------------
__global__ __launch_bounds__(256, 1) void fused_e(
    const ushort* __restrict__ EMB, const ushort* __restrict__ e1wt,
    const float* __restrict__ e1b, const ushort* __restrict__ e2wt,
    const float* __restrict__ e2b, const float* __restrict__ ar,
    ushort* __restrict__ AEb)
{
    __shared__ __align__(16) ushort Z1s[128 * 256];      // 64 KB
    __shared__ __align__(16) char  Stage[64 * 1024];     // 64 KB (As+Bs1 / Bs2)
    ushort* As  = (ushort*)Stage;                        // 128x32  (8 KB)
    ushort* Bs1 = (ushort*)(Stage + 8 * 1024);           // 256x32  (16 KB)
    ushort* Bs2 = (ushort*)Stage;                        // 128x256 (64 KB)

    const int tid  = threadIdx.x;
    const int lane = tid & 63;
    const int w    = tid >> 6;
    const int wr   = w >> 1, wc = w & 1;                 // 2x2 waves
    const int row0 = blockIdx.x * 128;
    const int mrd  = lane & 15;
    const int krd  = (lane >> 4) * 8;
    const int cn   = lane & 15;
    const int rb   = (lane >> 4) * 4;

    // stage A (128x32) and B1 (256x32)
#pragma unroll
    for (int id = tid; id < 512; id += 256)
        gld16(EMB + (size_t)(row0 + id / 4) * 32 + (id % 4) * 8, &As[id * 8]);
#pragma unroll
    for (int id = tid; id < 1024; id += 256)
        gld16(e1wt + (size_t)(id / 4) * 32 + (id % 4) * 8, &Bs1[id * 8]);
    __syncthreads();

    // phase 1: Z1 = relu(EMB@e1 + e1b), two 128-col passes, K=32 single MFMA
    bf16x8 afr[4];
#pragma unroll
    for (int tm = 0; tm < 4; tm++)
        afr[tm] = *(bf16x8*)(&As[(wr * 64 + tm * 16 + mrd) * 32 + krd]);
#pragma unroll
    for (int nc1 = 0; nc1 < 2; nc1++) {
        f32x4 acc[4][4];
#pragma unroll
        for (int tm = 0; tm < 4; tm++)
#pragma unroll
            for (int tn = 0; tn < 4; tn++) {
                bf16x8 bfr = *(bf16x8*)(&Bs1[(nc1 * 128 + wc * 64 + tn * 16 + mrd) * 32 + krd]);
                f32x4 z; z[0]=0.f; z[1]=0.f; z[2]=0.f; z[3]=0.f;
                acc[tm][tn] = __builtin_amdgcn_mfma_f32_16x16x32_bf16(afr[tm], bfr, z, 0, 0, 0);
            }
#pragma unroll
        for (int tm = 0; tm < 4; tm++)
#pragma unroll
            for (int r = 0; r < 4; r++) {
                int row = wr * 64 + tm * 16 + rb + r;
#pragma unroll
                for (int tn = 0; tn < 4; tn++) {
                    int col = nc1 * 128 + wc * 64 + tn * 16 + cn;
                    Z1s[row * 256 + col] = f2bf(fmaxf(acc[tm][tn][r] + e1b[col], 0.f));
                }
            }
    }
    __syncthreads();

    // phase 2: AE chunk-by-chunk over N=1024 (8 chunks of 128), K=256 from LDS
    for (int nc = 0; nc < 8; nc++) {
#pragma unroll
        for (int id = tid; id < 4096; id += 256)
            gld16(e2wt + (size_t)(nc * 128 + id / 32) * 256 + (id % 32) * 8, &Bs2[id * 8]);
        __syncthreads();
        f32x4 acc[4][4];
#pragma unroll
        for (int tm = 0; tm < 4; tm++)
#pragma unroll
            for (int tn = 0; tn < 4; tn++)
#pragma unroll
                for (int r = 0; r < 4; r++) acc[tm][tn][r] = 0.f;
#pragma unroll
        for (int kk = 0; kk < 256; kk += 32) {
            bf16x8 af[4], bf[4];
#pragma unroll
            for (int tm = 0; tm < 4; tm++)
                af[tm] = *(bf16x8*)(&Z1s[(wr * 64 + tm * 16 + mrd) * 256 + kk + krd]);
#pragma unroll
            for (int tn = 0; tn < 4; tn++)
                bf[tn] = *(bf16x8*)(&Bs2[(wc * 64 + tn * 16 + mrd) * 256 + kk + krd]);
#pragma unroll
            for (int tm = 0; tm < 4; tm++)
#pragma unroll
                for (int tn = 0; tn < 4; tn++)
                    acc[tm][tn] = __builtin_amdgcn_mfma_f32_16x16x32_bf16(
                        af[tm], bf[tn], acc[tm][tn], 0, 0, 0);
        }
        __syncthreads();
#pragma unroll
        for (int tm = 0; tm < 4; tm++)
#pragma unroll
            for (int r = 0; r < 4; r++) {
                int grow = row0 + wr * 64 + tm * 16 + rb + r;
                int b_   = grow & 511;
#pragma unroll
                for (int tn = 0; tn < 4; tn++) {
                    int col = nc * 128 + wc * 64 + tn * 16 + cn;
                    float v = acc[tm][tn][r] + e2b[col] + ar[(size_t)b_ * 1024 + col];
                    AEb[(size_t)(512 + grow) * 1024 + col] = f2bf(v);
                }
            }
    }
}

// ---------------------------------------------------------------------------
// fused_q: X[row] = relu(AE[row]@q1 + q1b)@q2 + q2b.  Y1 tile in LDS.
// Grid: 256 blocks of 256 threads.
// ---------------------------------------------------------------------------
__global__ __launch_bounds__(256, 1) void fused_q(
    const ushort* __restrict__ AEb, const ushort* __restrict__ q1wt,
    const float* __restrict__ q1b, const ushort* __restrict__ q2wt,
    const float* __restrict__ q2b, float* __restrict__ X)
{
    __shared__ __align__(16) ushort Y1s[128 * 256];      // 64 KB
    __shared__ __align__(16) char  Stage[48 * 1024];     // As 16K + Bs 32K / Bs2 16K
    ushort* As  = (ushort*)Stage;                        // 128x64
    ushort* Bs  = (ushort*)(Stage + 16 * 1024);          // 256x64
    ushort* Bs2 = (ushort*)Stage;                        // 32x256

    const int tid  = threadIdx.x;
    const int lane = tid & 63;
    const int w    = tid >> 6;
    const int wr   = w >> 1, wc = w & 1;                 // 2x2 waves for phase 1
    const int row0 = blockIdx.x * 128;
    const int mrd  = lane & 15;
    const int krd  = (lane >> 4) * 8;
    const int cn   = lane & 15;
    const int rb   = (lane >> 4) * 4;

    // phase 1: Y1(128x256) = relu(AE@q1 + q1b), K=1024, BK=64
    f32x4 acc[4][8];
#pragma unroll
    for (int tm = 0; tm < 4; tm++)
#pragma unroll
        for (int tn = 0; tn < 8; tn++)
#pragma unroll
            for (int r = 0; r < 4; r++) acc[tm][tn][r] = 0.f;

    for (int k0 = 0; k0 < 1024; k0 += 64) {
#pragma unroll
        for (int id = tid; id < 1024; id += 256)
            gld16(AEb + (size_t)(row0 + id / 8) * 1024 + k0 + (id % 8) * 8, &As[id * 8]);
#pragma unroll
        for (int id = tid; id < 2048; id += 256)
            gld16(q1wt + (size_t)(id / 8) * 1024 + k0 + (id % 8) * 8, &Bs[id * 8]);
        __syncthreads();
#pragma unroll
        for (int kk = 0; kk < 64; kk += 32) {
            bf16x8 af[4], bf[8];
#pragma unroll
            for (int tm = 0; tm < 4; tm++)
                af[tm] = *(bf16x8*)(&As[(wr * 64 + tm * 16 + mrd) * 64 + kk + krd]);
#pragma unroll
            for (int tn = 0; tn < 8; tn++)
                bf[tn] = *(bf16x8*)(&Bs[(wc * 128 + tn * 16 + mrd) * 64 + kk + krd]);
#pragma unroll
            for (int tm = 0; tm < 4; tm++)
#pragma unroll
                for (int tn = 0; tn < 8; tn++)
                    acc[tm][tn] = __builtin_amdgcn_mfma_f32_16x16x32_bf16(
                        af[tm], bf[tn], acc[tm][tn], 0, 0, 0);
        }
        __syncthreads();
    }
#pragma unroll
    for (int tm = 0; tm < 4; tm++)
#pragma unroll
        for (int r = 0; r < 4; r++) {
            int row = wr * 64 + tm * 16 + rb + r;
#pragma unroll
            for (int tn = 0; tn < 8; tn++) {
                int col = wc * 128 + tn * 16 + cn;
                Y1s[row * 256 + col] = f2bf(fmaxf(acc[tm][tn][r] + q1b[col], 0.f));
            }
        }
    // stage q2wt (32x256)
#pragma unroll
    for (int id = tid; id < 1024; id += 256)
        gld16(q2wt + (size_t)(id / 32) * 256 + (id % 32) * 8, &Bs2[id * 8]);
    __syncthreads();

    // phase 2: X(128x32) = Y1@q2 + q2b, K=256. 4 waves row-partitioned.
    f32x4 a2[2][2];
#pragma unroll
    for (int tm = 0; tm < 2; tm++)
#pragma unroll
        for (int tn = 0; tn < 2; tn++)
#pragma unroll
            for (int r = 0; r < 4; r++) a2[tm][tn][r] = 0.f;
#pragma unroll
    for (int kk = 0; kk < 256; kk += 32) {
        bf16x8 af[2], bf[2];
#pragma unroll
        for (int tm = 0; tm < 2; tm++)
            af[tm] = *(bf16x8*)(&Y1s[(w * 32 + tm * 16 + mrd) * 256 + kk + krd]);
#pragma unroll
        for (int tn = 0; tn < 2; tn++)
            bf[tn] = *(bf16x8*)(&Bs2[(tn * 16 + mrd) * 256 + kk + krd]);
#pragma unroll
        for (int tm = 0; tm < 2; tm++)
#pragma unroll
            for (int tn = 0; tn < 2; tn++)
                a2[tm][tn] = __builtin_amdgcn_mfma_f32_16x16x32_bf16(
                    af[tm], bf[tn], a2[tm][tn], 0, 0, 0);
    }
#pragma unroll
    for (int tm = 0; tm < 2; tm++)
#pragma unroll
        for (int r = 0; r < 4; r++) {
            int grow = row0 + w * 32 + tm * 16 + rb + r;
#pragma unroll
            for (int tn = 0; tn < 2; tn++) {
                int col = tn * 16 + cn;
                X[(size_t)grow * 32 + col] = a2[tm][tn][r] + q2b[col];
            }
        }
}

// ---------------------------------------------------------------------------
// misc_prep: ae_init (blocks 0..511) + all 5 weight transpose/cvt jobs
// ---------------------------------------------------------------------------
__global__ __launch_bounds__(256) void misc_prep(
    const float* __restrict__ kw,  const float* __restrict__ e1w,
    const float* __restrict__ e2w, const float* __restrict__ q1w,
    const float* __restrict__ q2w,
    ushort* __restrict__ kwt,  ushort* __restrict__ e1wt,
    ushort* __restrict__ e2wt, ushort* __restrict__ q1wt,
    ushort* __restrict__ q2wt,
    const float* __restrict__ ar, ushort* __restrict__ AEb)
{
    int bx = blockIdx.x;
    if (bx < 512) {
        int i = (bx * 256 + threadIdx.x) * 4;
        float4 v = *(const float4*)(ar + i);
        ushort4 o;
        o.x = f2bf(v.x); o.y = f2bf(v.y); o.z = f2bf(v.z); o.w = f2bf(v.w);
        *(ushort4*)(AEb + i) = o;
        return;
    }
    bx -= 512;
    const float* W; ushort* WT; int K, N, t0;
    if      (bx < 8)   { W = kw;  WT = kwt;  K = 256;  N = 32;   t0 = bx; }
    else if (bx < 16)  { W = e1w; WT = e1wt; K = 32;   N = 256;  t0 = bx - 8; }
    else if (bx < 272) { W = e2w; WT = e2wt; K = 256;  N = 1024; t0 = bx - 16; }
    else if (bx < 528) { W = q1w; WT = q1wt; K = 1024; N = 256;  t0 = bx - 272; }
    else               { W = q2w; WT = q2wt; K = 256;  N = 32;   t0 = bx - 528; }
    int nn = N >> 5;
    int kt = (t0 / nn) * 32, nt = (t0 % nn) * 32;
    __shared__ float t[32][33];
    int x = threadIdx.x & 31, y = threadIdx.x >> 5;
    for (int i = y; i < 32; i += 8) t[i][x] = W[(size_t)(kt + i) * N + nt + x];
    __syncthreads();
    for (int i = y; i < 32; i += 8) WT[(size_t)(nt + i) * K + kt + x] = f2bf(t[x][i]);
}

// ---------------------------------------------------------------------------
// prep: key fixup (bf16) + first-occurrence fs[b][n] + pooled EMB (bf16)
// ---------------------------------------------------------------------------
__global__ __launch_bounds__(64) void prep_kernel(
    const int* __restrict__ en_g, const int* __restrict__ su_g,
    const int* __restrict__ sun_g, ushort* __restrict__ key,
    const float* __restrict__ eemb,
    int* __restrict__ fs_g, ushort* __restrict__ EMB)
{
    int b = blockIdx.x;
    int tid = threadIdx.x;   // 64 = one wave
    __shared__ int fs_l[513];
    __shared__ int su_l[64];
    __shared__ float krows[64 * 32];
    for (int i = tid; i < 513; i += 64) fs_l[i] = 64;
    su_l[tid] = su_g[b * 64 + tid];
    int en = en_g[b];
    if (tid < 32) key[((size_t)b * 513 + 512) * 32 + tid] = 0;
    else          key[((size_t)b * 513 + en) * 32 + (tid - 32)] = f2bf(eemb[tid - 32]);
    __syncthreads();
    atomicMin(&fs_l[su_l[tid]], tid);
    unsigned long long ball = __ballot(su_l[tid] == en);
    int T = ball ? (__ffsll(ball) - 1) : 64;
    __syncthreads();
    {
        int d = tid & 31;
#pragma unroll 4
        for (int i = 0; i < 32; i++) {
            int r = 2 * i + (tid >> 5);
            krows[r * 32 + d] = bf2f(key[((size_t)b * 513 + su_l[r]) * 32 + d]);
        }
    }
    for (int i = tid; i < 513; i += 64) fs_g[(size_t)b * 513 + i] = fs_l[i];
    __syncthreads();

    int sun = sun_g[b];
    float a = 0.f;
    int cnt = 0;
    for (int i = 0; i < 64; i++) {
        bool nw = (i < T) && (fs_l[su_l[i]] == i);
        if (nw) {
            cnt++;
            if (tid < 32) a += krows[i * 32 + tid];
        }
        float denom = (sun != 0 && cnt > 0) ? (float)cnt : 1.0f;
        if (tid < 32) EMB[((size_t)i * 512 + b) * 32 + tid] = f2bf(a / denom);
    }
}

// ---------------------------------------------------------------------------
// LN-LSTM: one WAVE per batch, no barriers in the step loop.
// ---------------------------------------------------------------------------
__device__ inline float sigm(float x) { return 1.0f / (1.0f + expf(-x)); }

__global__ __launch_bounds__(128) void lstm_kernel(
    const float* __restrict__ X, const float* __restrict__ wih_g,
    const float* __restrict__ whh_g,
    const float* __restrict__ lnig, const float* __restrict__ lnib,
    const float* __restrict__ lnhg, const float* __restrict__ lnhb,
    const float* __restrict__ lncg, const float* __restrict__ lncb,
    float* __restrict__ Q)
{
    const int wv = threadIdx.x >> 6;
    const int lane = threadIdx.x & 63;
    const int b = blockIdx.x * 2 + wv;
    __shared__ float xs[2][64 * 32];
    {
        int d = lane & 31;
#pragma unroll 8
        for (int i = 0; i < 32; i++) {
            int s = 2 * i + (lane >> 5);
            xs[wv][s * 32 + d] = X[((size_t)s * 512 + b) * 32 + d];
        }
    }
    float w0[32], w1[32], u0[32], u1[32];
#pragma unroll
    for (int k = 0; k < 32; k++) {
        w0[k] = wih_g[k * 128 + lane];
        w1[k] = wih_g[k * 128 + lane + 64];
        u0[k] = whh_g[k * 128 + lane];
        u1[k] = whh_g[k * 128 + lane + 64];
    }
    const float gi0 = lnig[lane], gi1 = lnig[lane + 64];
    const float bi0 = lnib[lane], bi1 = lnib[lane + 64];
    const float gh0 = lnhg[lane], gh1 = lnhg[lane + 64];
    const float bh0 = lnhb[lane], bh1 = lnhb[lane + 64];
    const int j = lane & 31;
    const float gc = lncg[j], bc = lncb[j];
    float h = 0.f, c = 0.f;
    __syncthreads();

    const float* xrow = &xs[wv][0];
    for (int s = 0; s < 64; s++) {
        float ax0 = 0.f, ax1 = 0.f, ah0 = 0.f, ah1 = 0.f;
#pragma unroll
        for (int k = 0; k < 32; k++) {
            float xk = xrow[s * 32 + k];
            float hk = __shfl(h, k);
            ax0 += xk * w0[k]; ax1 += xk * w1[k];
            ah0 += hk * u0[k]; ah1 += hk * u1[k];
        }
        float r0 = ax0 + ax1, r1 = ax0 * ax0 + ax1 * ax1;
        float r2 = ah0 + ah1, r3 = ah0 * ah0 + ah1 * ah1;
#pragma unroll
        for (int m = 1; m <= 32; m <<= 1) {
            r0 += __shfl_xor(r0, m); r1 += __shfl_xor(r1, m);
            r2 += __shfl_xor(r2, m); r3 += __shfl_xor(r3, m);
        }
        float mx = r0 * (1.f / 128.f), vx = r1 * (1.f / 128.f) - mx * mx;
        float mh = r2 * (1.f / 128.f), vh = r3 * (1.f / 128.f) - mh * mh;
        float sx = rsqrtf(vx + 1e-5f), sh = rsqrtf(vh + 1e-5f);
        float g0 = (ax0 - mx) * sx * gi0 + bi0 + (ah0 - mh) * sh * gh0 + bh0;
        float g1 = (ax1 - mx) * sx * gi1 + bi1 + (ah1 - mh) * sh * gh1 + bh1;
        float igv = __shfl(g0, j),      fgv = __shfl(g0, j + 32);
        float cgv = __shfl(g1, j),      ogv = __shfl(g1, j + 32);
        float cc = sigm(fgv) * c + sigm(igv) * tanhf(cgv);
        float s0 = cc, s1 = cc * cc;
#pragma unroll
        for (int m = 1; m <= 32; m <<= 1) {
            s0 += __shfl_xor(s0, m); s1 += __shfl_xor(s1, m);
        }
        float mc = s0 * (1.f / 64.f), vc = s1 * (1.f / 64.f) - mc * mc;
        c = (cc - mc) * rsqrtf(vc + 1e-5f) * gc + bc;
        h = sigm(ogv) * tanhf(c);
        if (lane < 32) Q[((size_t)b * 64 + s) * 32 + lane] = h;
    }
}

// ---------------------------------------------------------------------------
// logits: out[b][s][n] = mask ? dot(Q[b][s], key_bf16[b][n]) : -1e9
// ---------------------------------------------------------------------------
__global__ __launch_bounds__(128) void logits_kernel(
    const ushort* __restrict__ key, const float* __restrict__ Q,
    const int* __restrict__ fs_g, const int* __restrict__ en_g,
    float* __restrict__ out)
{
    int b = blockIdx.x;
    int n0 = blockIdx.y * 128;
    int tid = threadIdx.x;
    __shared__ float Qs[64 * 32];
    __shared__ float Ks[128 * 33];
    for (int i = tid * 4; i < 2048; i += 512)
        *(float4*)(&Qs[i]) = *(const float4*)(Q + (size_t)b * 2048 + i);
    for (int g = tid; g < 1024; g += 128) {
        int e = g * 4, r = e >> 5, d = e & 31;
        int n = n0 + r;
        if (n < 513) {
            ushort4 k4 = *(const ushort4*)(key + ((size_t)b * 513 + n) * 32 + d);
            Ks[r * 33 + d + 0] = bf2f(k4.x);
            Ks[r * 33 + d + 1] = bf2f(k4.y);
            Ks[r * 33 + d + 2] = bf2f(k4.z);
            Ks[r * 33 + d + 3] = bf2f(k4.w);
        }
    }
    __syncthreads();
    int n = n0 + tid;
    if (n < 513) {
        int en = en_g[b];
        int f = fs_g[(size_t)b * 513 + n];
        float kreg[32];
#pragma unroll
        for (int d = 0; d < 32; d++) kreg[d] = Ks[tid * 33 + d];
        for (int s = 0; s < 64; s++) {
            float a = 0.f;
#pragma unroll
            for (int d = 0; d < 32; d++) a += Qs[s * 32 + d] * kreg[d];
            bool m = (s == 0) ? (n < en) : ((n <= en) && (f >= s));
            out[((size_t)b * 64 + s) * 513 + n] = m ? a : -1e9f;
        }
    }
}

// ---------------------------------------------------------------------------
extern "C" void kernel_launch(void* const* d_in, const int* in_sizes, int n_in,
                              void* d_out, int out_size, void* d_ws, size_t ws_size,
                              hipStream_t stream)
{
    const float* ee   = (const float*)d_in[0];
    const float* ar   = (const float*)d_in[1];
    const int*   en   = (const int*)d_in[2];
    const int*   su   = (const int*)d_in[3];
    const int*   sun  = (const int*)d_in[4];
    const float* kw   = (const float*)d_in[5];
    const float* kb   = (const float*)d_in[6];
    const float* q1w  = (const float*)d_in[7];
    const float* q1b  = (const float*)d_in[8];
    const float* q2w  = (const float*)d_in[9];
    const float* q2b  = (const float*)d_in[10];
    const float* e1w  = (const float*)d_in[11];
    const float* e1b  = (const float*)d_in[12];
    const float* e2w  = (const float*)d_in[13];
    const float* e2b  = (const float*)d_in[14];
    const float* eemb = (const float*)d_in[15];
    const float* wih  = (const float*)d_in[16];
    const float* whh  = (const float*)d_in[17];
    const float* lnig = (const float*)d_in[18];
    const float* lnib = (const float*)d_in[19];
    const float* lnhg = (const float*)d_in[20];
    const float* lnhb = (const float*)d_in[21];
    const float* lncg = (const float*)d_in[22];
    const float* lncb = (const float*)d_in[23];
    float* outp = (float*)d_out;

    char* p = (char*)d_ws;
    ushort* key  = (ushort*)p; p += (size_t)512 * 513 * 32 * 2;   // 16.8 MB
    ushort* AEb  = (ushort*)p; p += (size_t)32768 * 1024 * 2;     // 67 MB
    ushort* EMBb = (ushort*)p; p += (size_t)32768 * 32 * 2;       // 2 MB
    float*  X    = (float*)p;  p += (size_t)32768 * 32 * 4;       // 4 MB
    float*  Q    = (float*)p;  p += (size_t)32768 * 32 * 4;       // 4 MB
    int*    fs   = (int*)p;    p += (size_t)512 * 513 * 4;        // 1.05 MB
    ushort* kwt  = (ushort*)p; p += (size_t)32 * 256 * 2;
    ushort* e1wt = (ushort*)p; p += (size_t)256 * 32 * 2;
    ushort* e2wt = (ushort*)p; p += (size_t)1024 * 256 * 2;
    ushort* q1wt = (ushort*)p; p += (size_t)256 * 1024 * 2;
    ushort* q2wt = (ushort*)p; p += (size_t)32 * 256 * 2;

    // 0. ae_init + weight transposes
    misc_prep<<<1048, 256, 0, stream>>>(kw, e1w, e2w, q1w, q2w,
                                        kwt, e1wt, e2wt, q1wt, q2wt, ar, AEb);

    // 1. key(bf16) = ee @ kw + kb  (M=262144, N=32, K=256), KEYMODE layout
    mfma_gemm<128, 32, 32, 4, 1, false, true, true, true>
        <<<dim3(2048, 1), 256, 0, stream>>>(ee, 256, kwt, kb, key, 32, 256);
    // 2. key fixup + fs + pooled EMB
    prep_kernel<<<512, 64, 0, stream>>>(en, su, sun, key, eemb, fs, EMBb);

    // 3. fused e1+e2 -> AE rows 512..32767
    fused_e<<<252, 256, 0, stream>>>(EMBb, e1wt, e1b, e2wt, e2b, ar, AEb);
    // 4. fused q1+q2 -> X (all 32768 rows)
    fused_q<<<256, 256, 0, stream>>>(AEb, q1wt, q1b, q2wt, q2b, X);

    // 5. LN-LSTM over 64 steps -> queries
    lstm_kernel<<<256, 128, 0, stream>>>(X, wih, whh, lnig, lnib, lnhg, lnhb, lncg, lncb, Q);

    // 6. logits + mask
    logits_kernel<<<dim3(512, 5), 128, 0, stream>>>(key, Q, fs, en, outp);
}